// Round 1
// baseline (348.906 us; speedup 1.0000x reference)
//
#include <hip/hip_runtime.h>

// Sparsity_Checker: fused passthrough-copy + collector histogram.
// All four reference outputs derive from the 5-bin histogram of
// collector = sum_t spikes[t] (values 0..T):
//   unique_counts[k]  = hist[k]
//   coll_zero_frac    = hist[0] / total
//   sparsity_ratio    = (total*T - sum_k k*hist[k]) / (total*T)
// So a single read of the input suffices (memory-bound: ~411 MB traffic).

constexpr int T_STEPS = 4;

__global__ __launch_bounds__(256) void spike_stats_kernel(
    const float4* __restrict__ in, float4* __restrict__ out,
    unsigned int* __restrict__ hist, int nvec)
{
    __shared__ unsigned int lhist[5];
    if (threadIdx.x < 5) lhist[threadIdx.x] = 0u;
    __syncthreads();

    // packed histogram: 5 bins x 12 bits. Per-wave bin max = 64 lanes *
    // 4 elems * 13 iters = 3328 < 4096 at grid=1024x256 — no overflow.
    unsigned long long packed = 0ull;

    const int stride = gridDim.x * blockDim.x;
    for (int v = blockIdx.x * blockDim.x + threadIdx.x; v < nvec; v += stride) {
        float4 a0 = in[0 * nvec + v];
        float4 a1 = in[1 * nvec + v];
        float4 a2 = in[2 * nvec + v];
        float4 a3 = in[3 * nvec + v];
        out[0 * nvec + v] = a0;
        out[1 * nvec + v] = a1;
        out[2 * nvec + v] = a2;
        out[3 * nvec + v] = a3;
        // elements are exactly 0.0f or 1.0f -> sums are exact small ints
        int cx = (int)(a0.x + a1.x + a2.x + a3.x);
        int cy = (int)(a0.y + a1.y + a2.y + a3.y);
        int cz = (int)(a0.z + a1.z + a2.z + a3.z);
        int cw = (int)(a0.w + a1.w + a2.w + a3.w);
        packed += (1ull << (cx * 12)) + (1ull << (cy * 12))
                + (1ull << (cz * 12)) + (1ull << (cw * 12));
    }

    // wave-64 butterfly reduce of the packed histogram
#pragma unroll
    for (int off = 32; off > 0; off >>= 1)
        packed += __shfl_down(packed, off, 64);

    if ((threadIdx.x & 63) == 0) {
#pragma unroll
        for (int k = 0; k < 5; ++k)
            atomicAdd(&lhist[k], (unsigned int)((packed >> (12 * k)) & 0xFFFull));
    }
    __syncthreads();

    // 5 global atomics per block (1024 blocks total) — negligible contention
    if (threadIdx.x < 5)
        atomicAdd(&hist[threadIdx.x], lhist[threadIdx.x]);
}

__global__ void finalize_kernel(const unsigned int* __restrict__ hist,
                                float* __restrict__ tail, double total)
{
    if (threadIdx.x == 0 && blockIdx.x == 0) {
        double spikes_sum = 0.0;
#pragma unroll
        for (int k = 0; k < 5; ++k)
            spikes_sum += (double)k * (double)hist[k];
        double denom = total * (double)T_STEPS;
        tail[0] = (float)((denom - spikes_sum) / denom); // sparsity_ratio
        tail[1] = (float)((double)hist[0] / total);      // coll_zero_frac
#pragma unroll
        for (int k = 0; k < 5; ++k)
            tail[2 + k] = (float)hist[k];                // unique_counts (exact: < 2^24)
    }
}

extern "C" void kernel_launch(void* const* d_in, const int* in_sizes, int n_in,
                              void* d_out, int out_size, void* d_ws, size_t ws_size,
                              hipStream_t stream)
{
    const float* spikes = (const float*)d_in[0];
    float* out = (float*)d_out;

    const long n = (long)in_sizes[0];       // T*B*C*H*W = 51,380,224
    const long per_t = n / T_STEPS;         // 12,845,056 elements per timestep
    const int nvec = (int)(per_t / 4);      // 3,211,264 float4 per timestep

    unsigned int* hist = (unsigned int*)d_ws;
    hipMemsetAsync(d_ws, 0, 5 * sizeof(unsigned int), stream);

    // grid=1024 (4 blocks/CU): keeps per-wave packed bins < 4096 and keeps
    // the final global-atomic count tiny while still saturating HBM.
    spike_stats_kernel<<<dim3(1024), dim3(256), 0, stream>>>(
        (const float4*)spikes, (float4*)out, hist, nvec);

    finalize_kernel<<<dim3(1), dim3(64), 0, stream>>>(hist, out + n, (double)per_t);
}